// Round 2
// baseline (394.630 us; speedup 1.0000x reference)
//
#include <hip/hip_runtime.h>
#include <hip/hip_bf16.h>
#include <math.h>

#define NB 256
#define SS 512
#define LL 128

typedef short bf16x8 __attribute__((ext_vector_type(8)));
typedef float f32x4 __attribute__((ext_vector_type(4)));

typedef __attribute__((address_space(1))) const unsigned int GU32;
typedef __attribute__((address_space(3))) unsigned int LU32;

__device__ __forceinline__ short f2bf(float f) {
    __hip_bfloat16 h = __float2bfloat16(f);
    short s;
    __builtin_memcpy(&s, &h, 2);
    return s;
}

// Stage 32 feature rows (16 KB f32) global->LDS via direct-to-LDS DMA.
// LDS dst is wave-uniform; HW writes lane i's 16 B at dst + 16*i, matching
// the per-lane global src (src includes tid*4 floats).
__device__ __forceinline__ void stage32rows(const float* src, float* dst) {
#pragma unroll
    for (int i = 0; i < 16; ++i)
        __builtin_amdgcn_global_load_lds((GU32*)(src + i * 256),
                                         (LU32*)(dst + i * 256), 16, 0, 0);
}

// Exact power-of-2 rescale of an 8-vector state (no rounding error).
__device__ __forceinline__ void rescale8(float (&v)[8], int& eacc) {
    float s = ((v[0] + v[1]) + (v[2] + v[3])) + ((v[4] + v[5]) + (v[6] + v[7]));
    s += __shfl_xor(s, 1);
    s += __shfl_xor(s, 2);
    s += __shfl_xor(s, 4);
    s += __shfl_xor(s, 8);
    int ex;
    frexpf(s, &ex);
#pragma unroll
    for (int nt = 0; nt < 8; ++nt) v[nt] = ldexpf(v[nt], -ex);
    eacc += ex;
}

// One block = ONE WAVE = BOTH chains (fwd alpha + bwd beta) of one batch.
// grid = 256 -> 1 wave/CU. No barriers anywhere. The two chains are
// independent dependency graphs interleaved in one wave: one lgkmcnt(0)
// covers both publishes, the 8 fragment reads pipeline together, 64 MFMAs
// interleave (dep distance 16), and each chain's VALU epilogue hides under
// the other chain's MFMA latency. exp(T) and exp(T^T) both live in VGPRs
// (256 regs). Features f32, double-buffered 32-row LDS chunks per chain,
// prefetched 32 rounds ahead (one vmcnt(0) per 32 rounds).
__global__ __launch_bounds__(64, 1) void crf_chain_kernel(
    const float* __restrict__ feats,    // (B,S,L)
    const float* __restrict__ start_t,  // (L)
    const float* __restrict__ end_t,    // (L)
    const float* __restrict__ trans,    // (L,L)
    const int* __restrict__ mask,       // (B,S)
    const int* __restrict__ labels,     // (B,S)
    float* __restrict__ ws)
{
    const int b = blockIdx.x;
    const int tid = threadIdx.x;
    const int l15 = tid & 15;
    const int g = tid >> 4;

    __shared__ __align__(16) short imgF[2][LL];     // fwd u image, bf16, dbuf
    __shared__ __align__(16) short imgB[2][LL];     // bwd u image, bf16, dbuf
    __shared__ __align__(16) float fSF[2][32][LL];  // fwd feature chunks (32 KB)
    __shared__ __align__(16) float fSB[2][32][LL];  // bwd feature chunks (32 KB)
    __shared__ int lmask[SS];

    const float* fb = feats + (size_t)b * SS * LL;

    // ---- stage chunk 0: fwd rows 1..32, bwd rows 480..511 ----
    stage32rows(fb + 1 * LL + tid * 4, &fSF[0][0][0]);
    stage32rows(fb + 480 * LL + tid * 4, &fSB[0][0][0]);

    // ---- masks (same-wave LDS; compiler orders the RAW) ----
#pragma unroll
    for (int q = 0; q < 8; ++q) lmask[tid + 64 * q] = mask[b * SS + tid + 64 * q];

    // ---- exp(transition) B-fragments for both directions, all in VGPRs ----
    // fwd: B[k][n] = exp(T[k][n]); bwd: B[k=j][n=i] = exp(T[i][j]) (= T^T)
    bf16x8 BfF[8][4], BfB[8][4];
#pragma unroll
    for (int nt = 0; nt < 8; ++nt) {
        const int n = 16 * nt + l15;
#pragma unroll
        for (int kt = 0; kt < 4; ++kt) {
            bf16x8 frF, frB;
#pragma unroll
            for (int j = 0; j < 8; ++j) {
                const int k = 32 * kt + 8 * g + j;
                frF[j] = f2bf(__expf(trans[k * LL + n]));
                frB[j] = f2bf(__expf(trans[n * LL + k]));
            }
            BfF[nt][kt] = frF;
            BfB[nt][kt] = frB;
        }
    }

    // ---- chain states (position 16*nt + l15, replicated over g) ----
    float vF[8], vB[8];
#pragma unroll
    for (int nt = 0; nt < 8; ++nt) {
        const int p = 16 * nt + l15;
        vF[nt] = __expf(start_t[p] + fb[p]);   // alpha_0
        vB[nt] = __expf(end_t[p]);             // beta_511
    }

    asm volatile("s_waitcnt vmcnt(0)" ::: "memory");  // chunk 0 landed

    // ---- prefetch chunk 1: fwd rows 33..64, bwd rows 448..479 ----
    stage32rows(fb + 33 * LL + tid * 4, &fSF[1][0][0]);
    stage32rows(fb + 448 * LL + tid * 4, &fSB[1][0][0]);

    // ---- exp(features) for round 0: fwd row 1 (slot 0), bwd row 511 (slot 31) ----
    float eftF[8], eftB[8], pB[8];
#pragma unroll
    for (int nt = 0; nt < 8; ++nt) {
        eftF[nt] = __expf(fSF[0][0][16 * nt + l15]);
        eftB[nt] = __expf(fSB[0][31][16 * nt + l15]);
        pB[nt] = vB[nt] * eftB[nt];            // bwd publish value, precomputed
    }

    int eaF = 0, eaB = 0;

    for (int r = 0; r < 256; ++r) {
        // chunk c+1 (issued 31 rounds ago) must land before this round's
        // next-feature read crosses into it
        if ((r & 31) == 31 && r != 255)
            asm volatile("s_waitcnt vmcnt(0)" ::: "memory");
        // first round of chunk c: prefetch chunk c+1 for both chains
        if ((r & 31) == 0 && r != 0 && r <= 192) {
            const int cN = (r >> 5) + 1;
            stage32rows(fb + (size_t)(32 * cN + 1) * LL + tid * 4, &fSF[cN & 1][0][0]);
            stage32rows(fb + (size_t)(480 - 32 * cN) * LL + tid * 4, &fSB[cN & 1][0][0]);
        }

        int mF = lmask[r + 1];
        if (r == 255) mF = 0;                  // fwd dummy round
        const int mB = lmask[511 - r];

        // ---- publish both chains (each lane writes tiles 2g, 2g+1) ----
        // fwd publishes alpha_{t-1}; bwd publishes exp(f_t)*beta_t (pB)
        float weF = (g < 2) ? (g == 0 ? vF[0] : vF[2]) : (g == 2 ? vF[4] : vF[6]);
        float woF = (g < 2) ? (g == 0 ? vF[1] : vF[3]) : (g == 2 ? vF[5] : vF[7]);
        float weB = (g < 2) ? (g == 0 ? pB[0] : pB[2]) : (g == 2 ? pB[4] : pB[6]);
        float woB = (g < 2) ? (g == 0 ? pB[1] : pB[3]) : (g == 2 ? pB[5] : pB[7]);
        short* ibF = &imgF[r & 1][0];
        short* ibB = &imgB[r & 1][0];
        ibF[32 * g + l15] = f2bf(weF);
        ibF[32 * g + 16 + l15] = f2bf(woF);
        ibB[32 * g + l15] = f2bf(weB);
        ibB[32 * g + 16 + l15] = f2bf(woB);

        // one shared same-wave RAW drain for both chains
        asm volatile("s_waitcnt lgkmcnt(0)" ::: "memory");

        const bf16x8* ipF = (const bf16x8*)ibF;
        const bf16x8* ipB = (const bf16x8*)ibB;
        bf16x8 fa0 = ipF[g], fa1 = ipF[4 + g], fa2 = ipF[8 + g], fa3 = ipF[12 + g];
        bf16x8 ba0 = ipB[g], ba1 = ipB[4 + g], ba2 = ipB[8 + g], ba3 = ipB[12 + g];

        // next round's raw features (off the critical path)
        float fnF[8], fnB[8];
        const int rn = r + 1;
        if (rn < 256) {
            const float* pFf = &fSF[(rn >> 5) & 1][rn & 31][0];
            const float* pBf = &fSB[(rn >> 5) & 1][31 - (rn & 31)][0];
#pragma unroll
            for (int nt = 0; nt < 8; ++nt) {
                fnF[nt] = pFf[16 * nt + l15];
                fnB[nt] = pBf[16 * nt + l15];
            }
        }

        f32x4 cF[8], cB[8];
#pragma unroll
        for (int nt = 0; nt < 8; ++nt) {
            cF[nt] = (f32x4){0.f, 0.f, 0.f, 0.f};
            cB[nt] = (f32x4){0.f, 0.f, 0.f, 0.f};
        }
        // 64 MFMAs interleaved F/B: dep distance 16 per accumulator
#pragma unroll
        for (int nt = 0; nt < 8; ++nt) {
            cF[nt] = __builtin_amdgcn_mfma_f32_16x16x32_bf16(fa0, BfF[nt][0], cF[nt], 0, 0, 0);
            cB[nt] = __builtin_amdgcn_mfma_f32_16x16x32_bf16(ba0, BfB[nt][0], cB[nt], 0, 0, 0);
        }
#pragma unroll
        for (int nt = 0; nt < 8; ++nt) {
            cF[nt] = __builtin_amdgcn_mfma_f32_16x16x32_bf16(fa1, BfF[nt][1], cF[nt], 0, 0, 0);
            cB[nt] = __builtin_amdgcn_mfma_f32_16x16x32_bf16(ba1, BfB[nt][1], cB[nt], 0, 0, 0);
        }
#pragma unroll
        for (int nt = 0; nt < 8; ++nt) {
            cF[nt] = __builtin_amdgcn_mfma_f32_16x16x32_bf16(fa2, BfF[nt][2], cF[nt], 0, 0, 0);
            cB[nt] = __builtin_amdgcn_mfma_f32_16x16x32_bf16(ba2, BfB[nt][2], cB[nt], 0, 0, 0);
        }
#pragma unroll
        for (int nt = 0; nt < 8; ++nt) {
            cF[nt] = __builtin_amdgcn_mfma_f32_16x16x32_bf16(fa3, BfF[nt][3], cF[nt], 0, 0, 0);
            cB[nt] = __builtin_amdgcn_mfma_f32_16x16x32_bf16(ba3, BfB[nt][3], cB[nt], 0, 0, 0);
        }

        // ---- epilogues (all C rows equal -> reg0 is the matvec) ----
#pragma unroll
        for (int nt = 0; nt < 8; ++nt) {
            float candF = eftF[nt] * cF[nt][0];
            vF[nt] = mF ? candF : vF[nt];
            vB[nt] = mB ? cB[nt][0] : vB[nt];
        }

        // exp(features) for next round (overlaps with nothing critical)
        if (rn < 256) {
#pragma unroll
            for (int nt = 0; nt < 8; ++nt) {
                eftF[nt] = __expf(fnF[nt]);
                eftB[nt] = __expf(fnB[nt]);
            }
        }

        // ---- rescale every 8 rounds (exact power-of-2) ----
        if ((r & 7) == 7) {
            rescale8(vF, eaF);
            rescale8(vB, eaB);
        }

        // bwd publish value for next round (off next round's head)
#pragma unroll
        for (int nt = 0; nt < 8; ++nt) pB[nt] = vB[nt] * eftB[nt];
    }

    // ---- workspace layout ----
    float* av = ws;                      // alpha_255 (B,L)
    float* bv = ws + NB * LL;            // beta_255  (B,L)
    float* eFa = ws + 2 * NB * LL;       // fwd exponents (B)
    float* eBa = eFa + NB;               // bwd exponents (B)
    float* lognum = eBa + NB;            // numerator (B)

    if (g == 0) {
#pragma unroll
        for (int nt = 0; nt < 8; ++nt) {
            av[b * LL + 16 * nt + l15] = vF[nt];
            bv[b * LL + 16 * nt + l15] = vB[nt];
        }
    }
    if (tid == 0) {
        eFa[b] = (float)eaF;
        eBa[b] = (float)eaB;
    }

    // ---- numerator (gold path, fp32 exact), full 512 positions ----
    {
        const int* lb = labels + b * SS;
        const int* mb = mask + b * SS;
        float term = 0.f;
        int cnt = 0;
#pragma unroll
        for (int q = 0; q < 8; ++q) {
            const int tt = tid + 64 * q;
            int l = lb[tt];
            if ((unsigned)l >= LL) l = 0;
            const int m = mb[tt];
            cnt += (m != 0);
            if (tt == 0) {
                term += start_t[l] + fb[l];
            } else if (m) {
                int lp = lb[tt - 1];
                if ((unsigned)lp >= LL) lp = 0;
                term += trans[lp * LL + l] + fb[(size_t)tt * LL + l];
            }
        }
#pragma unroll
        for (int o = 1; o < 64; o <<= 1) {
            term += __shfl_xor(term, o);
            cnt += __shfl_xor(cnt, o);
        }
        if (tid == 0) {
            int sl = cnt - 1;
            sl = sl < 0 ? 0 : (sl >= SS ? SS - 1 : sl);
            int lt = lb[sl];
            if ((unsigned)lt >= LL) lt = 0;
            lognum[b] = term + end_t[lt];
        }
    }
}

// Combine: Z = sum_i alpha_255[i]*beta_255[i] * 2^(eF+eB); loss reduce.
__global__ __launch_bounds__(256) void crf_final_kernel(
    const float* __restrict__ ws, const float* __restrict__ conf,
    float* __restrict__ out)
{
    const int tid = threadIdx.x;  // = batch index
    const float* av = ws;
    const float* bv = ws + NB * LL;
    const float* eFa = ws + 2 * NB * LL;
    const float* eBa = eFa + NB;
    const float* ln = eBa + NB;

    const float4* a4 = (const float4*)(av + tid * LL);
    const float4* b4 = (const float4*)(bv + tid * LL);
    float dot = 0.f;
#pragma unroll 8
    for (int k = 0; k < 32; ++k) {
        float4 a = a4[k], bb = b4[k];
        dot += a.x * bb.x + a.y * bb.y + a.z * bb.z + a.w * bb.w;
    }
    float logZ = logf(dot) + 0.69314718055994531f * (eFa[tid] + eBa[tid]);
    float loss = (logZ - ln[tid]) * conf[tid] * (1.0f / NB);

#pragma unroll
    for (int o = 1; o < 64; o <<= 1) loss += __shfl_xor(loss, o);
    __shared__ float red[4];
    if ((tid & 63) == 0) red[tid >> 6] = loss;
    __syncthreads();
    if (tid == 0) out[0] = red[0] + red[1] + red[2] + red[3];
}

extern "C" void kernel_launch(void* const* d_in, const int* in_sizes, int n_in,
                              void* d_out, int out_size, void* d_ws, size_t ws_size,
                              hipStream_t stream) {
    const float* feats  = (const float*)d_in[0];
    const float* startt = (const float*)d_in[1];
    const float* endt   = (const float*)d_in[2];
    const float* trans  = (const float*)d_in[3];
    const float* conf   = (const float*)d_in[4];
    const int*   mask   = (const int*)d_in[5];
    const int*   labels = (const int*)d_in[6];
    float* out = (float*)d_out;
    float* ws = (float*)d_ws;  // needs (2*256*128 + 3*256) floats = ~266 KB

    hipLaunchKernelGGL(crf_chain_kernel, dim3(NB), dim3(64), 0, stream,
                       feats, startt, endt, trans, mask, labels, ws);
    hipLaunchKernelGGL(crf_final_kernel, dim3(1), dim3(256), 0, stream,
                       ws, conf, out);
}

// Round 3
// 296.782 us; speedup vs baseline: 1.3297x; 1.3297x over previous
//
#include <hip/hip_runtime.h>
#include <hip/hip_bf16.h>
#include <math.h>

#define NB 256
#define SS 512
#define LL 128

typedef short bf16x4 __attribute__((ext_vector_type(4)));
typedef float f32x4 __attribute__((ext_vector_type(4)));

__device__ __forceinline__ short f2bf(float f) {
    __hip_bfloat16 h = __float2bfloat16(f);
    short s;
    __builtin_memcpy(&s, &h, 2);
    return s;
}

// D = A*B + C for 16x16x16 bf16. C/D layout (row=4*hi+reg, col=lo) is
// IDENTICAL to the B layout (k=4*hi+j, col=lo) -> the output of one round is
// directly the B operand of the next: the recurrence never leaves registers.
#if __has_builtin(__builtin_amdgcn_mfma_f32_16x16x16bf16_1k)
#define MFMA1616(c, a, bb) \
    c = __builtin_amdgcn_mfma_f32_16x16x16bf16_1k(a, bb, c, 0, 0, 0)
#else
#define MFMA1616(c, a, bb) \
    asm("v_mfma_f32_16x16x16_bf16 %0, %1, %2, %0" : "+v"(c) : "v"(a), "v"(bb))
#endif

// One block = ONE WAVE = one chain (fwd or bwd) of one batch; grid 512.
// State u[128] lives in the B-operand layout: lane (hi=tid>>4, lo=tid&15)
// holds positions p = 16*nt + 4*hi + j (j=0..3) of each 16-tile nt,
// replicated across the 16 column lanes (lo). exp(T) lives in A-fragments
// (128 VGPRs). Per round: 64 MFMAs + in-register epilogue. The only LDS use
// is a 4-slot ring of exp(features) rows (cooperatively computed, read back
// as 4-address broadcast ds_read_b128) and the mask array. No barriers, no
// state LDS round-trip, no cross-lane ops except the 8-round rescale.
template <int ISB>
__device__ __forceinline__ void run_chain(
    const float* __restrict__ fb,       // this batch's features (S,L)
    const float* __restrict__ start_t,
    const float* __restrict__ end_t,
    const float* __restrict__ trans,
    float* __restrict__ eRing,          // LDS [4*LL]
    const int* __restrict__ lmask,      // LDS [SS]
    float* __restrict__ outv,           // av/bv row (L floats)
    float* __restrict__ oute)           // eFa/eBa slot
{
    const int tid = threadIdx.x;
    const int lo = tid & 15;
    const int hi = tid >> 4;

    // ---- A-fragments: exp(transition), whole 128x128 in VGPRs ----
    // fwd: out[n] = sum_k exp(T[k][n]) u[k]  -> A[i=n][k] = exp(T[k][n])
    // bwd: out[i] = sum_j exp(T[i][j]) u[j]  -> A[i][k=j] = exp(T[i][j])
    bf16x4 Af[8][8];
#pragma unroll
    for (int nt = 0; nt < 8; ++nt) {
#pragma unroll
        for (int kt = 0; kt < 8; ++kt) {
            bf16x4 fr;
#pragma unroll
            for (int j = 0; j < 4; ++j) {
                const int kpos = 16 * kt + 4 * hi + j;
                const int npos = 16 * nt + lo;
                const float tv = ISB ? trans[npos * LL + kpos]
                                     : trans[kpos * LL + npos];
                fr[j] = f2bf(__expf(tv));
            }
            Af[nt][kt] = fr;
        }
    }

    // ---- state init (f32, canonical) + B-fragment init (bf16) ----
    float v[8][4];
    bf16x4 Bf[8];
#pragma unroll
    for (int nt = 0; nt < 8; ++nt) {
        bf16x4 fr;
#pragma unroll
        for (int j = 0; j < 4; ++j) {
            const int p = 16 * nt + 4 * hi + j;
            if (ISB) {
                const float val = __expf(end_t[p]);            // beta_511
                v[nt][j] = val;
                fr[j] = f2bf(val * __expf(fb[(size_t)511 * LL + p]));  // pub_0
            } else {
                const float val = __expf(start_t[p] + fb[p]);  // alpha_0
                v[nt][j] = val;
                fr[j] = f2bf(val);
            }
        }
        Bf[nt] = fr;
    }

    // ---- feature-exp ring prologue ----
    // row consumed at round r: fwd r+1, bwd 510-r. Slot r&3 holds that row.
    {
        const int r0 = ISB ? 510 : 1;   // round 0
        const int r1 = ISB ? 509 : 2;   // round 1
        const float2 a = *(const float2*)(fb + (size_t)r0 * LL + 2 * tid);
        const float2 bq = *(const float2*)(fb + (size_t)r1 * LL + 2 * tid);
        *(float2*)(eRing + 0 * LL + 2 * tid) = make_float2(__expf(a.x), __expf(a.y));
        *(float2*)(eRing + 1 * LL + 2 * tid) = make_float2(__expf(bq.x), __expf(bq.y));
    }
    float2 cur = *(const float2*)(fb + (size_t)(ISB ? 508 : 3) * LL + 2 * tid);
    float2 nxt = *(const float2*)(fb + (size_t)(ISB ? 507 : 4) * LL + 2 * tid);

    int eacc = 0;

    for (int r = 0; r < 256; ++r) {
        // ---- eft for THIS round: 8 broadcast ds_read_b128 from slot r&3
        //      (written 2 rounds ago; consumed after the MFMA block) ----
        const float* rp = eRing + (r & 3) * LL + 4 * hi;
        f32x4 eft[8];
#pragma unroll
        for (int nt = 0; nt < 8; ++nt)
            eft[nt] = *(const f32x4*)(rp + 16 * nt);

        // ---- pipeline: exp+publish row for round r+2; prefetch row r+4 ----
        *(float2*)(eRing + ((r + 2) & 3) * LL + 2 * tid) =
            make_float2(__expf(cur.x), __expf(cur.y));
        cur = nxt;
        {
            const int rowN = ISB ? (506 - r) : (r + 5);  // always in [0,512)
            nxt = *(const float2*)(fb + (size_t)rowN * LL + 2 * tid);
        }

        int mt = lmask[ISB ? (511 - r) : (r + 1)];

        // ---- 64 MFMAs: cc[nt] += A[nt][kt] * B[kt], 8 indep chains ----
        f32x4 cc[8];
#pragma unroll
        for (int nt = 0; nt < 8; ++nt) cc[nt] = (f32x4){0.f, 0.f, 0.f, 0.f};
#pragma unroll
        for (int kt = 0; kt < 8; ++kt) {
#pragma unroll
            for (int nt = 0; nt < 8; ++nt)
                MFMA1616(cc[nt], Af[nt][kt], Bf[kt]);
        }

        if (!ISB && r == 255) mt = 0;  // fwd dummy round

        // ---- epilogue, all in registers ----
        // fwd: cand = exp(f_t) * (T^T u);  bwd: cand = T * pub
#pragma unroll
        for (int nt = 0; nt < 8; ++nt) {
#pragma unroll
            for (int j = 0; j < 4; ++j) {
                const float cand = ISB ? cc[nt][j] : eft[nt][j] * cc[nt][j];
                v[nt][j] = mt ? cand : v[nt][j];
            }
        }

        // ---- exact power-of-2 rescale every 8 rounds ----
        if ((r & 7) == 7) {
            float s = 0.f;
#pragma unroll
            for (int nt = 0; nt < 8; ++nt)
#pragma unroll
                for (int j = 0; j < 4; ++j) s += v[nt][j];
            s += __shfl_xor(s, 16);   // combine hi pairs (cols are replicas)
            s += __shfl_xor(s, 32);
            int ex;
            frexpf(s, &ex);
#pragma unroll
            for (int nt = 0; nt < 8; ++nt)
#pragma unroll
                for (int j = 0; j < 4; ++j) v[nt][j] = ldexpf(v[nt][j], -ex);
            eacc += ex;
        }

        // ---- pack next B: fwd publishes state; bwd publishes exp(f)*state ----
#pragma unroll
        for (int nt = 0; nt < 8; ++nt) {
            bf16x4 fr;
#pragma unroll
            for (int j = 0; j < 4; ++j)
                fr[j] = f2bf(ISB ? eft[nt][j] * v[nt][j] : v[nt][j]);
            Bf[nt] = fr;
        }
    }

    // ---- export (cols are replicas: lo==0 lanes write) ----
    if (lo == 0) {
#pragma unroll
        for (int nt = 0; nt < 8; ++nt) {
            f32x4 o = {v[nt][0], v[nt][1], v[nt][2], v[nt][3]};
            *(f32x4*)(outv + 16 * nt + 4 * hi) = o;
        }
    }
    if (tid == 0) *oute = (float)eacc;
}

__global__ __launch_bounds__(64, 1) void crf_chain_kernel(
    const float* __restrict__ feats,    // (B,S,L)
    const float* __restrict__ start_t,  // (L)
    const float* __restrict__ end_t,    // (L)
    const float* __restrict__ trans,    // (L,L)
    const int* __restrict__ mask,       // (B,S)
    const int* __restrict__ labels,     // (B,S)
    float* __restrict__ ws)
{
    const int bid = blockIdx.x;
    const int b = bid & 255;
    const int isB = bid >> 8;   // 0 = forward chain, 1 = backward chain
    const int tid = threadIdx.x;

    __shared__ __align__(16) float eRing[4 * LL];  // 2 KB
    __shared__ int lmask[SS];                      // 2 KB

    // stage masks (same-wave LDS; in-order DS makes the RAW safe)
#pragma unroll
    for (int q = 0; q < 8; ++q) lmask[tid + 64 * q] = mask[b * SS + tid + 64 * q];

    const float* fb = feats + (size_t)b * SS * LL;

    float* av = ws;                      // alpha_255 (B,L)
    float* bv = ws + NB * LL;            // beta_255  (B,L)
    float* eFa = ws + 2 * NB * LL;       // fwd exponents (B)
    float* eBa = eFa + NB;               // bwd exponents (B)
    float* lognum = eBa + NB;            // numerator (B)

    if (isB)
        run_chain<1>(fb, start_t, end_t, trans, eRing, lmask, bv + b * LL, eBa + b);
    else
        run_chain<0>(fb, start_t, end_t, trans, eRing, lmask, av + b * LL, eFa + b);

    // ---- numerator (gold path, fp32 exact), bwd block only ----
    if (isB) {
        const int* lb = labels + b * SS;
        const int* mb = mask + b * SS;
        float term = 0.f;
        int cnt = 0;
#pragma unroll
        for (int q = 0; q < 8; ++q) {
            const int tt = tid + 64 * q;
            int l = lb[tt];
            if ((unsigned)l >= LL) l = 0;
            const int m = mb[tt];
            cnt += (m != 0);
            if (tt == 0) {
                term += start_t[l] + fb[l];
            } else if (m) {
                int lp = lb[tt - 1];
                if ((unsigned)lp >= LL) lp = 0;
                term += trans[lp * LL + l] + fb[(size_t)tt * LL + l];
            }
        }
#pragma unroll
        for (int o = 1; o < 64; o <<= 1) {
            term += __shfl_xor(term, o);
            cnt += __shfl_xor(cnt, o);
        }
        if (tid == 0) {
            int sl = cnt - 1;
            sl = sl < 0 ? 0 : (sl >= SS ? SS - 1 : sl);
            int lt = lb[sl];
            if ((unsigned)lt >= LL) lt = 0;
            lognum[b] = term + end_t[lt];
        }
    }
}

// Combine: Z = sum_i alpha_255[i]*beta_255[i] * 2^(eF+eB); loss reduce.
__global__ __launch_bounds__(256) void crf_final_kernel(
    const float* __restrict__ ws, const float* __restrict__ conf,
    float* __restrict__ out)
{
    const int tid = threadIdx.x;  // = batch index
    const float* av = ws;
    const float* bv = ws + NB * LL;
    const float* eFa = ws + 2 * NB * LL;
    const float* eBa = eFa + NB;
    const float* ln = eBa + NB;

    const float4* a4 = (const float4*)(av + tid * LL);
    const float4* b4 = (const float4*)(bv + tid * LL);
    float dot = 0.f;
#pragma unroll 8
    for (int k = 0; k < 32; ++k) {
        float4 a = a4[k], bb = b4[k];
        dot += a.x * bb.x + a.y * bb.y + a.z * bb.z + a.w * bb.w;
    }
    float logZ = logf(dot) + 0.69314718055994531f * (eFa[tid] + eBa[tid]);
    float loss = (logZ - ln[tid]) * conf[tid] * (1.0f / NB);

#pragma unroll
    for (int o = 1; o < 64; o <<= 1) loss += __shfl_xor(loss, o);
    __shared__ float red[4];
    if ((tid & 63) == 0) red[tid >> 6] = loss;
    __syncthreads();
    if (tid == 0) out[0] = red[0] + red[1] + red[2] + red[3];
}

extern "C" void kernel_launch(void* const* d_in, const int* in_sizes, int n_in,
                              void* d_out, int out_size, void* d_ws, size_t ws_size,
                              hipStream_t stream) {
    const float* feats  = (const float*)d_in[0];
    const float* startt = (const float*)d_in[1];
    const float* endt   = (const float*)d_in[2];
    const float* trans  = (const float*)d_in[3];
    const float* conf   = (const float*)d_in[4];
    const int*   mask   = (const int*)d_in[5];
    const int*   labels = (const int*)d_in[6];
    float* out = (float*)d_out;
    float* ws = (float*)d_ws;  // needs (2*256*128 + 3*256) floats = ~266 KB

    hipLaunchKernelGGL(crf_chain_kernel, dim3(2 * NB), dim3(64), 0, stream,
                       feats, startt, endt, trans, mask, labels, ws);
    hipLaunchKernelGGL(crf_final_kernel, dim3(1), dim3(256), 0, stream,
                       ws, conf, out);
}